// Round 5
// baseline (160.808 us; speedup 1.0000x reference)
//
#include <hip/hip_runtime.h>
#include <hip/hip_bf16.h>
#include <cstdint>
#include <cstddef>

// Problem constants
#define CNU 500000      // item id offset
#define CB  65536       // batch
#define CE  128         // embedding dim
#define CF  172         // feature dim
#define EV  64          // events per block (4 M-tiles of 16)

typedef unsigned short ushort_t;
typedef __attribute__((ext_vector_type(8))) short b8;    // 8 x bf16
typedef __attribute__((ext_vector_type(4))) short b4;    // 4 x bf16
typedef __attribute__((ext_vector_type(4))) float f4;    // MFMA accumulator

#define MFMA16(a,b,c) __builtin_amdgcn_mfma_f32_16x16x32_bf16((a),(b),(c),0,0,0)

// ---- packed weight layout in ws (ushort elements), B-fragment order:
// frag(nt,kt): lane l holds B[k=kt*32+(l>>4)*8+j][n=nt*16+(l&15)], j=0..7
#define FRAG 512
#define U_KT 18                   // 14 k-tiles wih (K pad 448) + 4 whh
#define U_NT 24
#define U_SZ (U_NT*U_KT*FRAG)
#define PU_OFF 0
#define PI_OFF U_SZ
#define PG_OFF (2*U_SZ)
#define G_SZ (8*8*FRAG)
#define PP_OFF (PG_OFF + G_SZ)
#define P_SZ (8*4*FRAG)

// XOR-swizzle on 16B granules, both write and read sides (T2 discipline).
#define SWZ(r, c) ((c) ^ (((r) & 7) << 3))
#define AFRAG(T, r, c) (*(const b8*)&(T)[(r)][SWZ((r), (c))])

__device__ __forceinline__ unsigned pk2bf(float a, float b) {
  __hip_bfloat162 h = __float22bfloat162_rn(make_float2(a, b));   // v_cvt_pk_bf16_f32
  return *reinterpret_cast<unsigned*>(&h);
}
__device__ __forceinline__ ushort_t f2bf(float f) {
  unsigned u = __float_as_uint(f);
  return (ushort_t)((u + 0x7FFFu + ((u >> 16) & 1u)) >> 16);   // RNE (scalar fallback)
}
__device__ __forceinline__ float bf2f(ushort_t h) {
  return __uint_as_float(((unsigned)h) << 16);
}
__device__ __forceinline__ float sigmoid_(float x) { return 1.0f/(1.0f+__expf(-x)); }
__device__ __forceinline__ float tanh_(float x) { float e=__expf(2.0f*x); return 1.0f-2.0f/(e+1.0f); }

// ---- LDS: [EV][128] bf16 sub-tiles, 256B rows, XOR-swizzled.
// Tile reuse: QU hosts h'_u after pred; PU hosts h'_i after gi.
struct __align__(16) SLds {
  ushort_t PU[EV][128];   // proj_user  -> h'_i
  ushort_t PI[EV][128];   // proj_item
  ushort_t FE[EV][192];   // features (cols 172-191 zero)
  ushort_t OU[EV][128];   // old_user (h_u)
  ushort_t OI[EV][128];   // old_item (h_i)
  ushort_t QU[EV][128];   // query_user -> h'_u
};                        // 106,496 B -> 1 block/CU (but 16 waves)

extern "C" __global__ void prep_weights(
    const float* __restrict__ u_wih, const float* __restrict__ u_whh,
    const float* __restrict__ i_wih, const float* __restrict__ i_whh,
    const float* __restrict__ gate_w, const float* __restrict__ pred_w,
    ushort_t* __restrict__ ws)
{
  const int stride = gridDim.x * blockDim.x;
  const int tid = blockIdx.x * blockDim.x + threadIdx.x;
  for (int i = tid; i < U_SZ; i += stride) {
    const int nt = i / (U_KT*FRAG);
    const int r1 = i - nt*(U_KT*FRAG);
    const int kt = r1 / FRAG;
    const int e  = r1 - kt*FRAG;
    const int l  = e >> 3, j = e & 7;
    const int n  = nt*16 + (l & 15);
    const int k  = (l >> 4)*8 + j;
    float vu, vi;
    if (kt < 14) {
      const int kk = kt*32 + k;
      vu = (kk < 428) ? u_wih[(size_t)n*428 + kk] : 0.0f;
      vi = (kk < 428) ? i_wih[(size_t)n*428 + kk] : 0.0f;
    } else {
      const int kk = (kt - 14)*32 + k;
      vu = u_whh[(size_t)n*128 + kk];
      vi = i_whh[(size_t)n*128 + kk];
    }
    ws[PU_OFF + i] = f2bf(vu);
    ws[PI_OFF + i] = f2bf(vi);
  }
  for (int i = tid; i < G_SZ; i += stride) {
    const int nt = i / (8*FRAG);
    const int r1 = i - nt*(8*FRAG);
    const int kt = r1 / FRAG;
    const int e  = r1 - kt*FRAG;
    const int l  = e >> 3, j = e & 7;
    const int n  = nt*16 + (l & 15);
    const int kk = kt*32 + (l >> 4)*8 + j;
    ws[PG_OFF + i] = f2bf(gate_w[(size_t)n*256 + kk]);
  }
  for (int i = tid; i < P_SZ; i += stride) {
    const int nt = i / (4*FRAG);
    const int r1 = i - nt*(4*FRAG);
    const int kt = r1 / FRAG;
    const int e  = r1 - kt*FRAG;
    const int l  = e >> 3, j = e & 7;
    const int n  = nt*16 + (l & 15);
    const int kk = kt*32 + (l >> 4)*8 + j;
    ws[PP_OFF + i] = f2bf(pred_w[(size_t)n*128 + kk]);
  }
}

// 16 waves: g = wave>>3 selects GRU (0=user,+pred; 1=item); wv = wave&7 selects
// gate columns {wv, wv+8, wv+16}. Each wave: 64-acc-VGPR GRU -> <=128 VGPR
// -> 4 waves/SIMD for latency hiding (R4 post-mortem: latency-bound at 2/SIMD).
extern "C" __global__ void __launch_bounds__(1024, 4)
jodie_main(const int* __restrict__ user_ids, const int* __restrict__ item_ids,
           const float* __restrict__ timestamps, const float* __restrict__ features,
           const int* __restrict__ query_time, const float* __restrict__ memv,
           const float* __restrict__ last_time, const float* __restrict__ time_w,
           const float* __restrict__ u_bih, const float* __restrict__ u_bhh,
           const float* __restrict__ i_bih, const float* __restrict__ i_bhh,
           const float* __restrict__ gate_b, const float* __restrict__ pred_b,
           const ushort_t* __restrict__ ws, float* __restrict__ d_out)
{
  __shared__ SLds s;
  const int t  = threadIdx.x;
  const int e0 = blockIdx.x * EV;

  // ---- stage: 16 threads/event, 8 cols each, one pass (1024 thr = 64 ev) ----
  {
    const int c8 = (t & 15) * 8;
    const int e  = t >> 4;
    const int ge = e0 + e;
    const float qt = (float)query_time[0];
    const float4 tw0 = *(const float4*)&time_w[c8];
    const float4 tw1 = *(const float4*)&time_w[c8 + 4];
    const float twv[8] = {tw0.x,tw0.y,tw0.z,tw0.w, tw1.x,tw1.y,tw1.z,tw1.w};

    const int u   = user_ids[ge];
    const int itn = item_ids[ge] + CNU;
    const float ts = timestamps[ge];
    const float lu = last_time[u];
    const float li = last_time[itn];
    const float du = ts - lu, di = ts - li, dq = qt - lu;

    const float4 ou0 = *(const float4*)&memv[(size_t)u  *CE + c8];
    const float4 ou1 = *(const float4*)&memv[(size_t)u  *CE + c8 + 4];
    const float4 oi0 = *(const float4*)&memv[(size_t)itn*CE + c8];
    const float4 oi1 = *(const float4*)&memv[(size_t)itn*CE + c8 + 4];
    const float ouv[8] = {ou0.x,ou0.y,ou0.z,ou0.w, ou1.x,ou1.y,ou1.z,ou1.w};
    const float oiv[8] = {oi0.x,oi0.y,oi0.z,oi0.w, oi1.x,oi1.y,oi1.z,oi1.w};

    union U8 { unsigned q[4]; b8 v; };
    U8 xu, xi, hu, hi, qv;
#pragma unroll
    for (int j = 0; j < 8; j += 2) {
      xu.q[j>>1] = pk2bf(ouv[j]*(1.0f + du*twv[j]), ouv[j+1]*(1.0f + du*twv[j+1]));
      xi.q[j>>1] = pk2bf(oiv[j]*(1.0f + di*twv[j]), oiv[j+1]*(1.0f + di*twv[j+1]));
      hu.q[j>>1] = pk2bf(ouv[j], ouv[j+1]);
      hi.q[j>>1] = pk2bf(oiv[j], oiv[j+1]);
      qv.q[j>>1] = pk2bf(ouv[j]*(1.0f + dq*twv[j]), ouv[j+1]*(1.0f + dq*twv[j+1]));
    }
    *(b8*)&s.PU[e][SWZ(e, c8)] = xu.v;
    *(b8*)&s.PI[e][SWZ(e, c8)] = xi.v;
    *(b8*)&s.OU[e][SWZ(e, c8)] = hu.v;
    *(b8*)&s.OI[e][SWZ(e, c8)] = hi.v;
    *(b8*)&s.QU[e][SWZ(e, c8)] = qv.v;
  }
  // ---- features: exact float4 tiling (172 = 43*4) ----
  for (int i = t; i < EV*43; i += 1024) {
    const int e = i / 43, q = i - e*43;
    const float4 fv = *(const float4*)&features[(size_t)(e0 + e)*CF + q*4];
    union { unsigned q[2]; b4 v; } fb;
    fb.q[0] = pk2bf(fv.x, fv.y);
    fb.q[1] = pk2bf(fv.z, fv.w);
    *(b4*)&s.FE[e][SWZ(e, q*4)] = fb.v;
  }
  for (int i = t; i < EV*20; i += 1024) {
    const int e = i / 20, c = 172 + (i - e*20);
    s.FE[e][SWZ(e, c)] = 0;
  }
  __syncthreads();

  const int w    = t >> 6;        // 0..15
  const int g    = w >> 3;        // 0 = user GRU (+pred), 1 = item GRU
  const int wv   = w & 7;
  const int l    = t & 63;
  const int lrow = l & 15;
  const int lk   = (l >> 4) * 8;
  const int col  = wv*16 + lrow;

  const float* bih = g ? i_bih : u_bih;
  const float* bhh = g ? i_bhh : u_bhh;
  const ushort_t* WB = ws + (g ? PI_OFF : PU_OFF);
  const ushort_t* Wr = WB + (size_t)(wv     )*U_KT*FRAG + l*8;
  const ushort_t* Wz = WB + (size_t)(wv +  8)*U_KT*FRAG + l*8;
  const ushort_t* Wn = WB + (size_t)(wv + 16)*U_KT*FRAG + l*8;

  // ---- pred (user waves only; QU reused as h'_u after B2) ----
  if (g == 0) {
    const float bp = pred_b[col];
    f4 ap[4];
#pragma unroll
    for (int m = 0; m < 4; ++m) ap[m] = (f4){bp,bp,bp,bp};
    const ushort_t* WP = ws + PP_OFF + (size_t)wv*4*FRAG + l*8;
#pragma unroll
    for (int kt = 0; kt < 4; ++kt) {
      b8 fp = *(const b8*)(WP + (size_t)kt*FRAG);
#pragma unroll
      for (int m = 0; m < 4; ++m) {
        b8 a = AFRAG(s.QU, m*16 + lrow, 32*kt + lk);
        ap[m] = MFMA16(a, fp, ap[m]);
      }
    }
#pragma unroll
    for (int m = 0; m < 4; ++m)
#pragma unroll
      for (int r4 = 0; r4 < 4; ++r4) {
        const int row = m*16 + (l >> 4)*4 + r4;
        d_out[(size_t)(e0 + row)*CE + col] = ap[m][r4];
      }
  }

  // ---- GRU accumulators (one GRU per wave group: 64 acc VGPRs) ----
  const float br = bih[col]     + bhh[col];
  const float bz = bih[col+128] + bhh[col+128];
  const float bn = bih[col+256];
  const float bh = bhh[col+256];
  f4 ar[4], az[4], an[4], ah[4];
#pragma unroll
  for (int m = 0; m < 4; ++m) {
    ar[m] = (f4){br,br,br,br};
    az[m] = (f4){bz,bz,bz,bz};
    an[m] = (f4){bn,bn,bn,bn};
    ah[m] = (f4){bh,bh,bh,bh};
  }

  // ---- gi: K=448 over [own-proj | peer-proj | features] ----
#pragma unroll
  for (int pf = 0; pf < 14; ++pf) {
    b8 a_[4];
    if (pf < 8) {
      // pf<4: own projection (user:PU, item:PI); pf 4-7: peer projection
      const ushort_t (*A)[128] = ((pf < 4) ^ g) ? s.PU : s.PI;
      const int c = 32*(pf & 3);
#pragma unroll
      for (int m = 0; m < 4; ++m) a_[m] = AFRAG(A, m*16 + lrow, c + lk);
    } else {
      const int c = 32*(pf - 8);
#pragma unroll
      for (int m = 0; m < 4; ++m) a_[m] = AFRAG(s.FE, m*16 + lrow, c + lk);
    }
    b8 fr = *(const b8*)(Wr + (size_t)pf*FRAG);
    b8 fz = *(const b8*)(Wz + (size_t)pf*FRAG);
    b8 fn = *(const b8*)(Wn + (size_t)pf*FRAG);
#pragma unroll
    for (int m = 0; m < 4; ++m) {
      ar[m] = MFMA16(a_[m], fr, ar[m]);
      az[m] = MFMA16(a_[m], fz, az[m]);
      an[m] = MFMA16(a_[m], fn, an[m]);
    }
  }

  // ---- gh: K=128 over h (r,z continue; n-side into ah) ----
  {
    const ushort_t (*H)[128] = g ? s.OI : s.OU;
#pragma unroll
    for (int kt = 0; kt < 4; ++kt) {
      b8 fr = *(const b8*)(Wr + (size_t)(14+kt)*FRAG);
      b8 fz = *(const b8*)(Wz + (size_t)(14+kt)*FRAG);
      b8 fn = *(const b8*)(Wn + (size_t)(14+kt)*FRAG);
#pragma unroll
      for (int m = 0; m < 4; ++m) {
        b8 h = AFRAG(H, m*16 + lrow, 32*kt + lk);
        ar[m] = MFMA16(h, fr, ar[m]);
        az[m] = MFMA16(h, fz, az[m]);
        ah[m] = MFMA16(h, fn, ah[m]);
      }
    }
  }
  __syncthreads();   // pred reads of QU + gi reads of PU/PI/FE complete

  // ---- elementwise: h' -> LDS (user->QU, item->PU); keep h/h' in regs ----
  float hv[16], hpv[16];
  {
    ushort_t (*DST)[128] = g ? s.PU : s.QU;
    const ushort_t (*H)[128] = g ? s.OI : s.OU;
#pragma unroll
    for (int m = 0; m < 4; ++m)
#pragma unroll
      for (int r4 = 0; r4 < 4; ++r4) {
        const int row = m*16 + (l >> 4)*4 + r4;
        const float rr = sigmoid_(ar[m][r4]);
        const float zz = sigmoid_(az[m][r4]);
        const float nn = tanh_(an[m][r4] + rr*ah[m][r4]);
        const float h  = bf2f(H[row][SWZ(row, col)]);
        const float hp = (1.0f - zz)*nn + zz*h;
        hv [m*4 + r4] = h;
        hpv[m*4 + r4] = hp;
        DST[row][SWZ(row, col)] = f2bf(hp);
      }
  }
  __syncthreads();   // h'_u (QU) and h'_i (PU) visible

  // ---- memory gate: sigmoid([h | h'] @ gate_w^T + b), epilogue from regs ----
  {
    const float gb = gate_b[col];
    f4 ag[4];
#pragma unroll
    for (int m = 0; m < 4; ++m) ag[m] = (f4){gb,gb,gb,gb};
    const ushort_t* WG = ws + PG_OFF + (size_t)wv*8*FRAG + l*8;
    const ushort_t (*HO)[128] = g ? s.OI : s.OU;
    const ushort_t (*HN)[128] = g ? s.PU : s.QU;
#pragma unroll
    for (int kt = 0; kt < 8; ++kt) {
      b8 fg = *(const b8*)(WG + (size_t)kt*FRAG);
#pragma unroll
      for (int m = 0; m < 4; ++m) {
        b8 a = (kt < 4) ? AFRAG(HO, m*16 + lrow, 32*kt + lk)
                        : AFRAG(HN, m*16 + lrow, 32*(kt-4) + lk);
        ag[m] = MFMA16(a, fg, ag[m]);
      }
    }
    float* __restrict__ outp = d_out + (size_t)(1 + g)*CB*CE;
#pragma unroll
    for (int m = 0; m < 4; ++m)
#pragma unroll
      for (int r4 = 0; r4 < 4; ++r4) {
        const int row = m*16 + (l >> 4)*4 + r4;
        const float gg = sigmoid_(ag[m][r4]);
        outp[(size_t)(e0 + row)*CE + col] = gg*hpv[m*4 + r4] + (1.0f - gg)*hv[m*4 + r4];
      }
  }
}

extern "C" void kernel_launch(void* const* d_in, const int* in_sizes, int n_in,
                              void* d_out, int out_size, void* d_ws, size_t ws_size,
                              hipStream_t stream) {
  const int*   user_ids   = (const int*)d_in[0];
  const int*   item_ids   = (const int*)d_in[1];
  const float* timestamps = (const float*)d_in[2];
  const float* features   = (const float*)d_in[3];
  const int*   query_time = (const int*)d_in[4];
  const float* memv       = (const float*)d_in[5];
  const float* last_time  = (const float*)d_in[6];
  const float* time_w     = (const float*)d_in[7];
  const float* u_wih = (const float*)d_in[8];
  const float* u_whh = (const float*)d_in[9];
  const float* u_bih = (const float*)d_in[10];
  const float* u_bhh = (const float*)d_in[11];
  const float* i_wih = (const float*)d_in[12];
  const float* i_whh = (const float*)d_in[13];
  const float* i_bih = (const float*)d_in[14];
  const float* i_bhh = (const float*)d_in[15];
  const float* gate_w = (const float*)d_in[16];
  const float* gate_b = (const float*)d_in[17];
  const float* pred_w = (const float*)d_in[18];
  const float* pred_b = (const float*)d_in[19];
  ushort_t* ws = (ushort_t*)d_ws;
  float* out = (float*)d_out;

  prep_weights<<<dim3(256), dim3(256), 0, stream>>>(u_wih, u_whh, i_wih, i_whh,
                                                    gate_w, pred_w, ws);
  jodie_main<<<dim3(CB/EV), dim3(1024), 0, stream>>>(user_ids, item_ids, timestamps,
                                                     features, query_time, memv,
                                                     last_time, time_w,
                                                     u_bih, u_bhh, i_bih, i_bhh,
                                                     gate_b, pred_b, ws, out);
}